// Round 1
// baseline (1035.027 us; speedup 1.0000x reference)
//
#include <hip/hip_runtime.h>
#include <hip/hip_bf16.h>

typedef __bf16 bf16x8 __attribute__((ext_vector_type(8)));
typedef float f32x4 __attribute__((ext_vector_type(4)));
typedef unsigned short u16x4 __attribute__((ext_vector_type(4)));
typedef unsigned short u16x8 __attribute__((ext_vector_type(8)));

#define EPS 1e-8f
#define TAU_INV 10.0f

#define BM 256
#define BN 512
#define BK 32
#define LSTRIDE 516              // 512 + 4 pad for epilogue fp32 tile

#define A_U16 8192               // A tile per K-step: 256 rows * 32 k (u16)
#define B_U16 16384              // B tile per K-step: 512 cols * 32 k (u16)
#define BUF_U16 (A_U16 + B_U16)  // 24576 u16 = 48 KB per buffer
#define BSTEP 16384              // u16 per kt-block in swizzled B

// async global->LDS, 16B per lane, dest = wave-uniform base + lane*16
__device__ __forceinline__ void gload_lds16(const void* g, void* l) {
    __builtin_amdgcn_global_load_lds(
        (const __attribute__((address_space(1))) void*)g,
        (__attribute__((address_space(3))) void*)l,
        16, 0, 0);
}

__device__ __forceinline__ u16x4 cvt_bf16x4(float4 v) {
    u16x4 u;
    u[0] = __builtin_bit_cast(unsigned short, __float2bfloat16(v.x));
    u[1] = __builtin_bit_cast(unsigned short, __float2bfloat16(v.y));
    u[2] = __builtin_bit_cast(unsigned short, __float2bfloat16(v.z));
    u[3] = __builtin_bit_cast(unsigned short, __float2bfloat16(v.w));
    return u;
}

// ---------------------------------------------------------------------------
// prep: centers -> bf16 in MFMA-granule-swizzled order + inv norms (unchanged).
// Bsw granule g = 16B at ((kt*32 + nt)*64 + r16 + q*16)*8 u16,
// holding B[row][kt*32 + q*8 .. +8]. One wave per row; lane i owns k=i*16..+16.
// ---------------------------------------------------------------------------
__global__ __launch_bounds__(256) void prep_centers_kernel(
    const float* __restrict__ cen, unsigned short* __restrict__ Bsw,
    float* __restrict__ inv_c, int K, int D)
{
    const int wave = threadIdx.x >> 6;
    const int lane = threadIdx.x & 63;
    const int row  = blockIdx.x * 4 + wave;
    if (row >= K) return;

    const float* src = cen + (size_t)row * D + lane * 16;
    const int kt = lane >> 1;
    const int nt = row >> 4;
    const int r16 = row & 15;
    const int q0 = (lane & 1) * 2;

    float ss = 0.0f;
    u16x8 g[2];
    #pragma unroll
    for (int h = 0; h < 2; ++h) {
        #pragma unroll
        for (int j = 0; j < 2; ++j) {
            float4 v = *(const float4*)(src + h * 8 + j * 4);
            ss += v.x * v.x + v.y * v.y + v.z * v.z + v.w * v.w;
            g[h][j * 4 + 0] = __builtin_bit_cast(unsigned short, __float2bfloat16(v.x));
            g[h][j * 4 + 1] = __builtin_bit_cast(unsigned short, __float2bfloat16(v.y));
            g[h][j * 4 + 2] = __builtin_bit_cast(unsigned short, __float2bfloat16(v.z));
            g[h][j * 4 + 3] = __builtin_bit_cast(unsigned short, __float2bfloat16(v.w));
        }
        size_t off = ((size_t)(kt * 32 + nt) * 64 + r16 + (q0 + h) * 16) * 8;
        *(u16x8*)(Bsw + off) = g[h];
    }
    #pragma unroll
    for (int off = 32; off; off >>= 1) ss += __shfl_xor(ss, off);
    if (lane == 0)
        inv_c[row] = (1.0f / fmaxf(sqrtf(ss), EPS)) * TAU_INV; // fold 1/tau
}

// ---------------------------------------------------------------------------
// fused GEMM + log-softmax + NLL.
// 256x512 tile (full center width), 1024 threads = 16 waves, grid = N/256 = 256
// = exactly 1 block/CU. Each wave owns a 64x128 output tile: acc[4][8].
// Per K-step: ~2500 cyc of MFMA per CU -> HBM A-latency and the per-barrier
// vmcnt drain amortize; B L2->LDS staging cut 4x vs the BM=64 version.
// ---------------------------------------------------------------------------
__global__ __launch_bounds__(1024, 4) void gemm_loss_kernel(
    const float* __restrict__ Afp, const unsigned short* __restrict__ Bsw,
    const float* __restrict__ inv_c, const int* __restrict__ labels,
    float* __restrict__ out, int N, int D)
{
    __shared__ union {
        unsigned short t[2 * BUF_U16];   // staging: [buf][A(16KB) | B(32KB)]
        float L[64 * LSTRIDE];           // epilogue overlay (129 KB)
    } sm;
    __shared__ float inv_e_s[BM];
    __shared__ int   lab_s[BM];
    __shared__ float blockLoss;

    const int tid  = threadIdx.x;
    const int wave = tid >> 6;          // 0..15
    const int lane = tid & 63;
    const int quad = lane >> 4;
    const int tq   = lane & 15;
    const int wm   = wave >> 2;         // row quadrant: rows wm*64..+64
    const int wn   = wave & 3;          // col quadrant: cols wn*128..+128
    const int blockRow = blockIdx.x * BM;

    // ---- A staging map: thread owns rows {ar, ar+128}, float4 slice aj ----
    const int ar   = tid >> 3;          // 0..127
    const int aj   = tid & 7;           // 0..7
    const int a_q  = aj >> 1, a_jl = aj & 1;
    const int a_r16 = ar & 15;
    const int a_woff0 = ((ar >> 4) * 64 + a_q * 16 + (a_r16 ^ (2 * a_q))) * 8 + a_jl * 4;
    const int a_woff1 = a_woff0 + 4096;           // row+128 -> tile+8 -> +8*64*8 u16
    const float* ag0 = Afp + (size_t)(blockRow + ar) * D + aj * 4;
    const float* ag1 = ag0 + (size_t)128 * D;

    // ---- B staging: wave w DMAs nt-tiles {2w, 2w+1}; contiguous 1KB per instr ----
    const unsigned short* bg0 = Bsw + (2 * wave + 0) * 512 + lane * 8;
    const unsigned short* bg1 = Bsw + (2 * wave + 1) * 512 + lane * 8;
    const int b_dst0 = A_U16 + (2 * wave + 0) * 512;   // wave-uniform LDS base (u16)
    const int b_dst1 = A_U16 + (2 * wave + 1) * 512;

    // ---- fragment read offsets (buffer-relative u16, kt-invariant) ----
    int aro[4], bro[8];
    #pragma unroll
    for (int mt = 0; mt < 4; ++mt)
        aro[mt] = ((wm * 4 + mt) * 64 + quad * 16 + (tq ^ (2 * quad))) * 8;
    #pragma unroll
    for (int nt = 0; nt < 8; ++nt)
        bro[nt] = A_U16 + ((wn * 8 + nt) * 64 + lane) * 8;

    f32x4 acc[4][8];
    #pragma unroll
    for (int mt = 0; mt < 4; ++mt)
        #pragma unroll
        for (int nt = 0; nt < 8; ++nt)
            acc[mt][nt] = (f32x4){0.f, 0.f, 0.f, 0.f};
    float ssq0 = 0.0f, ssq1 = 0.0f;
    if (tid == 0) blockLoss = 0.0f;

    const int nK = D / BK;   // 32

    // ---- prologue: stage kt=0 into buf0 ----
    {
        float4 v0 = *(const float4*)ag0;            // oldest vm ops: consumable
        float4 v1 = *(const float4*)ag1;            // at vmcnt(2)
        gload_lds16(bg0, &sm.t[b_dst0]);
        gload_lds16(bg1, &sm.t[b_dst1]);
        ssq0 += v0.x * v0.x + v0.y * v0.y + v0.z * v0.z + v0.w * v0.w;
        ssq1 += v1.x * v1.x + v1.y * v1.y + v1.z * v1.z + v1.w * v1.w;
        *(u16x4*)&sm.t[a_woff0] = cvt_bf16x4(v0);
        *(u16x4*)&sm.t[a_woff1] = cvt_bf16x4(v1);
    }

    for (int kt = 0; kt < nK; ++kt) {
        __syncthreads();   // buf[kt] staged & visible; buf[kt+1] free
        unsigned short* cur = &sm.t[(kt & 1) * BUF_U16];
        unsigned short* nxt = &sm.t[((kt + 1) & 1) * BUF_U16];

        float4 v0, v1;
        const bool hn = (kt + 1) < nK;
        if (hn) {
            v0 = *(const float4*)(ag0 + (kt + 1) * BK);   // A prefetch (oldest vm ops)
            v1 = *(const float4*)(ag1 + (kt + 1) * BK);
            gload_lds16(bg0 + (size_t)(kt + 1) * BSTEP, nxt + b_dst0);
            gload_lds16(bg1 + (size_t)(kt + 1) * BSTEP, nxt + b_dst1);
        }

        bf16x8 af[4], bfv[8];
        #pragma unroll
        for (int mt = 0; mt < 4; ++mt) af[mt]  = *(const bf16x8*)(cur + aro[mt]);
        #pragma unroll
        for (int nt = 0; nt < 8; ++nt) bfv[nt] = *(const bf16x8*)(cur + bro[nt]);
        #pragma unroll
        for (int mt = 0; mt < 4; ++mt)
            #pragma unroll
            for (int nt = 0; nt < 8; ++nt)
                acc[mt][nt] = __builtin_amdgcn_mfma_f32_16x16x32_bf16(
                    af[mt], bfv[nt], acc[mt][nt], 0, 0, 0);

        if (hn) {   // A-load latency hidden behind the MFMA block
            ssq0 += v0.x * v0.x + v0.y * v0.y + v0.z * v0.z + v0.w * v0.w;
            ssq1 += v1.x * v1.x + v1.y * v1.y + v1.z * v1.z + v1.w * v1.w;
            *(u16x4*)(nxt + a_woff0) = cvt_bf16x4(v0);
            *(u16x4*)(nxt + a_woff1) = cvt_bf16x4(v1);
        }
    }

    // ---- row inverse norms: reduce 8 k-slice partials per row ----
    ssq0 += __shfl_xor(ssq0, 1); ssq0 += __shfl_xor(ssq0, 2); ssq0 += __shfl_xor(ssq0, 4);
    ssq1 += __shfl_xor(ssq1, 1); ssq1 += __shfl_xor(ssq1, 2); ssq1 += __shfl_xor(ssq1, 4);
    if (aj == 0) {
        inv_e_s[ar]       = 1.0f / fmaxf(sqrtf(ssq0), EPS);
        inv_e_s[ar + 128] = 1.0f / fmaxf(sqrtf(ssq1), EPS);
    }
    if (tid < BM) lab_s[tid] = labels[blockRow + tid];

    float ic[8];
    #pragma unroll
    for (int nt = 0; nt < 8; ++nt)
        ic[nt] = inv_c[wn * 128 + nt * 16 + tq];

    __syncthreads();   // inv_e_s/lab_s ready; all frag reads retired -> L overlay safe

    float ie[4][4];
    #pragma unroll
    for (int mt = 0; mt < 4; ++mt)
        #pragma unroll
        for (int r = 0; r < 4; ++r)
            ie[mt][r] = inv_e_s[wm * 64 + mt * 16 + quad * 4 + r];

    const float invN = 1.0f / (float)N;

    // ---- epilogue: 4 groups of 64 rows; scale + logsumexp + NLL ----
    for (int gb = 0; gb < 4; ++gb) {
        if (wm == gb) {
            #pragma unroll
            for (int mt = 0; mt < 4; ++mt)
                #pragma unroll
                for (int nt = 0; nt < 8; ++nt)
                    #pragma unroll
                    for (int r = 0; r < 4; ++r)
                        sm.L[(mt * 16 + quad * 4 + r) * LSTRIDE + wn * 128 + nt * 16 + tq]
                            = acc[mt][nt][r] * ie[mt][r] * ic[nt];
        }
        __syncthreads();
        #pragma unroll
        for (int rr = 0; rr < 4; ++rr) {
            const int rl = wave * 4 + rr;           // 0..63
            float vals[8];
            float vmax = -3.0e38f;
            #pragma unroll
            for (int j = 0; j < 8; ++j) {
                vals[j] = sm.L[rl * LSTRIDE + j * 64 + lane];
                vmax = fmaxf(vmax, vals[j]);
            }
            #pragma unroll
            for (int off = 32; off; off >>= 1) vmax = fmaxf(vmax, __shfl_xor(vmax, off));
            float s = 0.0f;
            #pragma unroll
            for (int j = 0; j < 8; ++j) s += __expf(vals[j] - vmax);
            #pragma unroll
            for (int off = 32; off; off >>= 1) s += __shfl_xor(s, off);
            if (lane == 0) {
                int lab = lab_s[gb * 64 + rl];
                float ll = sm.L[rl * LSTRIDE + lab];
                atomicAdd(&blockLoss, vmax + __logf(s) - ll);
            }
        }
        __syncthreads();   // L free for next group; also orders blockLoss
    }
    if (tid == 0) atomicAdd(out, blockLoss * invN);
}

// ---------------------------------------------------------------------------
extern "C" void kernel_launch(void* const* d_in, const int* in_sizes, int n_in,
                              void* d_out, int out_size, void* d_ws, size_t ws_size,
                              hipStream_t stream)
{
    const float* emb = (const float*)d_in[0];
    const float* cen = (const float*)d_in[1];
    const int* labels = (const int*)d_in[2];
    float* out = (float*)d_out;

    const int N = in_sizes[2];
    const int D = in_sizes[0] / N;
    const int K = in_sizes[1] / D;

    char* ws = (char*)d_ws;
    unsigned short* Bsw = (unsigned short*)ws;              // K*D*2 bytes, swizzled
    float* inv_c = (float*)(ws + (size_t)K * D * 2);        // K floats

    hipMemsetAsync(d_out, 0, sizeof(float), stream);

    prep_centers_kernel<<<(K + 3) / 4, 256, 0, stream>>>(cen, Bsw, inv_c, K, D);

    gemm_loss_kernel<<<N / BM, 1024, 0, stream>>>(emb, Bsw, inv_c, labels, out, N, D);
}

// Round 2
// 414.014 us; speedup vs baseline: 2.5000x; 2.5000x over previous
//
#include <hip/hip_runtime.h>
#include <hip/hip_bf16.h>

typedef __bf16 bf16x8 __attribute__((ext_vector_type(8)));
typedef float f32x4 __attribute__((ext_vector_type(4)));
typedef unsigned short u16x4 __attribute__((ext_vector_type(4)));
typedef unsigned short u16x8 __attribute__((ext_vector_type(8)));

#define EPS 1e-8f
#define TAU_INV 10.0f

#define BM 64
#define BN 512
#define BK 32
#define LSTRIDE 516              // 512 + 4 pad for epilogue fp32 tile
#define ABUF 2048                // u16 per A buffer: 64 rows * 32 k

__device__ __forceinline__ u16x4 cvt_bf16x4(float4 v) {
    u16x4 u;
    u[0] = __builtin_bit_cast(unsigned short, __float2bfloat16(v.x));
    u[1] = __builtin_bit_cast(unsigned short, __float2bfloat16(v.y));
    u[2] = __builtin_bit_cast(unsigned short, __float2bfloat16(v.z));
    u[3] = __builtin_bit_cast(unsigned short, __float2bfloat16(v.w));
    return u;
}

// ---------------------------------------------------------------------------
// prep: centers -> bf16 in MFMA-granule-swizzled order + inv norms.
// Bsw granule (kt,nt,q): 16B at ((kt*32 + nt)*64 + r16 + q*16)*8 u16,
// holding B[row][kt*32 + q*8 .. +8]. One wave per row; lane i owns k=i*16..+16.
// This is EXACT per-wave MFMA B-fragment order: a wave's fragment for
// (kt, nt) is the contiguous 1KB at ((kt*32+nt)*64 + lane)*8.
// ---------------------------------------------------------------------------
__global__ __launch_bounds__(256) void prep_centers_kernel(
    const float* __restrict__ cen, unsigned short* __restrict__ Bsw,
    float* __restrict__ inv_c, int K, int D)
{
    const int wave = threadIdx.x >> 6;
    const int lane = threadIdx.x & 63;
    const int row  = blockIdx.x * 4 + wave;
    if (row >= K) return;

    const float* src = cen + (size_t)row * D + lane * 16;
    const int kt = lane >> 1;
    const int nt = row >> 4;
    const int r16 = row & 15;
    const int q0 = (lane & 1) * 2;

    float ss = 0.0f;
    u16x8 g[2];
    #pragma unroll
    for (int h = 0; h < 2; ++h) {
        #pragma unroll
        for (int j = 0; j < 2; ++j) {
            float4 v = *(const float4*)(src + h * 8 + j * 4);
            ss += v.x * v.x + v.y * v.y + v.z * v.z + v.w * v.w;
            g[h][j * 4 + 0] = __builtin_bit_cast(unsigned short, __float2bfloat16(v.x));
            g[h][j * 4 + 1] = __builtin_bit_cast(unsigned short, __float2bfloat16(v.y));
            g[h][j * 4 + 2] = __builtin_bit_cast(unsigned short, __float2bfloat16(v.z));
            g[h][j * 4 + 3] = __builtin_bit_cast(unsigned short, __float2bfloat16(v.w));
        }
        size_t off = ((size_t)(kt * 32 + nt) * 64 + r16 + (q0 + h) * 16) * 8;
        *(u16x8*)(Bsw + off) = g[h];
    }
    #pragma unroll
    for (int off = 32; off; off >>= 1) ss += __shfl_xor(ss, off);
    if (lane == 0)
        inv_c[row] = (1.0f / fmaxf(sqrtf(ss), EPS)) * TAU_INV; // fold 1/tau
}

// ---------------------------------------------------------------------------
// fused GEMM + log-softmax + NLL.
// 64 rows x all 512 centers; 512 threads = 8 waves, wave w owns cols w*64..+64.
// B fragments load global->VGPR directly (Bsw is fragment-ordered, 1KB
// coalesced per wave-load, L2-resident) -- NO B LDS round trip.
// Only A (fp32->bf16 convert + ssq) goes through LDS, double-buffered.
// LDS traffic/step: ~36KB (was ~100KB) << HBM pace; barrier drains only A.
// ---------------------------------------------------------------------------
__global__ __launch_bounds__(512, 4) void gemm_loss_kernel(
    const float* __restrict__ Afp, const unsigned short* __restrict__ Bsw,
    const float* __restrict__ inv_c, const int* __restrict__ labels,
    float* __restrict__ out, int N, int D)
{
    __shared__ union {
        unsigned short t[2 * ABUF];    // A staging (8 KB)
        float L[16 * LSTRIDE];         // epilogue overlay (33 KB)
    } sm;
    __shared__ float inv_e_s[BM];
    __shared__ float blockLoss;

    const int tid  = threadIdx.x;
    const int wave = tid >> 6;
    const int lane = tid & 63;
    const int quad = lane >> 4;
    const int tq   = lane & 15;
    const int blockRow = blockIdx.x * BM;

    // ---- A staging map: thread owns (row=tid>>3, float4 slice aj=tid&7) ----
    const int ar   = tid >> 3;        // 0..63
    const int aj   = tid & 7;         // 0..7
    const int a_q  = aj >> 1, a_jl = aj & 1;
    const int a_r16 = ar & 15;
    const int a_woff = (ar >> 4) * 512 + ((a_r16 ^ (2 * a_q)) + a_q * 16) * 8 + a_jl * 4;
    const float* ag = Afp + (size_t)(blockRow + ar) * D + aj * 4;

    // ---- B fragment base: wave's nt tiles are wave*4 + i (i=0..3) ----
    // frag(kt, i) = 16B at bbase + kt*16384 + i*512   (u16 units)
    const unsigned short* bbase = Bsw + (size_t)(wave * 4) * 512 + lane * 8;

    // ---- A fragment read offsets (buffer-relative, kt-invariant) ----
    const int a_rslot = (tq ^ (2 * quad)) + quad * 16;
    int aro[4];
    #pragma unroll
    for (int mt = 0; mt < 4; ++mt) aro[mt] = mt * 512 + a_rslot * 8;

    f32x4 acc[4][4];
    #pragma unroll
    for (int mt = 0; mt < 4; ++mt)
        #pragma unroll
        for (int nt = 0; nt < 4; ++nt)
            acc[mt][nt] = (f32x4){0.f, 0.f, 0.f, 0.f};
    float ssq = 0.0f;
    if (tid == 0) blockLoss = 0.0f;

    const int nK = D / BK;   // 32

    // ---- prologue: stage A kt=0 into buf0 ----
    {
        float4 v = *(const float4*)ag;
        ssq += v.x * v.x + v.y * v.y + v.z * v.z + v.w * v.w;
        *(u16x4*)&sm.t[a_woff] = cvt_bf16x4(v);
    }

    for (int kt = 0; kt < nK; ++kt) {
        __syncthreads();   // A buf[kt] staged & visible; buf[kt+1] free
        unsigned short* cur = &sm.t[(kt & 1) * ABUF];
        unsigned short* nxt = &sm.t[((kt + 1) & 1) * ABUF];

        // B fragments for this kt: 4 coalesced 1KB wave-loads, L2-resident
        bf16x8 bfv[4];
        const unsigned short* bk = bbase + (size_t)kt * 16384;
        #pragma unroll
        for (int i = 0; i < 4; ++i)
            bfv[i] = *(const bf16x8*)(bk + i * 512);

        float4 v;
        const bool hn = (kt + 1) < nK;
        if (hn) v = *(const float4*)(ag + (kt + 1) * BK);   // A prefetch

        bf16x8 af[4];
        #pragma unroll
        for (int mt = 0; mt < 4; ++mt) af[mt] = *(const bf16x8*)(cur + aro[mt]);

        #pragma unroll
        for (int nt = 0; nt < 4; ++nt)     // nt-outer: bfv[nt] needed latest
            #pragma unroll
            for (int mt = 0; mt < 4; ++mt)
                acc[mt][nt] = __builtin_amdgcn_mfma_f32_16x16x32_bf16(
                    af[mt], bfv[nt], acc[mt][nt], 0, 0, 0);

        if (hn) {   // A-load latency hidden behind the MFMA block
            ssq += v.x * v.x + v.y * v.y + v.z * v.z + v.w * v.w;
            *(u16x4*)(nxt + a_woff) = cvt_bf16x4(v);
        }
    }

    // ---- row inverse norms: reduce 8 k-slice partials per row ----
    ssq += __shfl_xor(ssq, 1);
    ssq += __shfl_xor(ssq, 2);
    ssq += __shfl_xor(ssq, 4);
    if (aj == 0) inv_e_s[ar] = 1.0f / fmaxf(sqrtf(ssq), EPS);

    // ---- epilogue: scale + per-16-row logsumexp + NLL ----
    float ic[4];
    #pragma unroll
    for (int nt = 0; nt < 4; ++nt)
        ic[nt] = inv_c[wave * 64 + nt * 16 + tq];
    const float invN = 1.0f / (float)N;

    for (int g = 0; g < 4; ++g) {
        __syncthreads();
        float ie[4];
        #pragma unroll
        for (int r = 0; r < 4; ++r)
            ie[r] = inv_e_s[g * 16 + quad * 4 + r];
        #pragma unroll
        for (int nt = 0; nt < 4; ++nt) {
            int col = wave * 64 + nt * 16 + tq;
            #pragma unroll
            for (int r = 0; r < 4; ++r)
                sm.L[(quad * 4 + r) * LSTRIDE + col] = acc[g][nt][r] * ie[r] * ic[nt];
        }
        __syncthreads();
        #pragma unroll
        for (int rr = 0; rr < 2; ++rr) {
            int rl = wave * 2 + rr;
            int grow = blockRow + g * 16 + rl;
            float vals[8];
            float vmax = -3.0e38f;
            #pragma unroll
            for (int j = 0; j < 8; ++j) {
                vals[j] = sm.L[rl * LSTRIDE + j * 64 + lane];
                vmax = fmaxf(vmax, vals[j]);
            }
            #pragma unroll
            for (int off = 32; off; off >>= 1) vmax = fmaxf(vmax, __shfl_xor(vmax, off));
            float s = 0.0f;
            #pragma unroll
            for (int j = 0; j < 8; ++j) s += __expf(vals[j] - vmax);
            #pragma unroll
            for (int off = 32; off; off >>= 1) s += __shfl_xor(s, off);
            if (lane == 0) {
                int lab = labels[grow];
                float ll = sm.L[rl * LSTRIDE + lab];
                atomicAdd(&blockLoss, vmax + __logf(s) - ll);
            }
        }
    }
    __syncthreads();
    if (tid == 0) atomicAdd(out, blockLoss * invN);
}

// ---------------------------------------------------------------------------
extern "C" void kernel_launch(void* const* d_in, const int* in_sizes, int n_in,
                              void* d_out, int out_size, void* d_ws, size_t ws_size,
                              hipStream_t stream)
{
    const float* emb = (const float*)d_in[0];
    const float* cen = (const float*)d_in[1];
    const int* labels = (const int*)d_in[2];
    float* out = (float*)d_out;

    const int N = in_sizes[2];
    const int D = in_sizes[0] / N;
    const int K = in_sizes[1] / D;

    char* ws = (char*)d_ws;
    unsigned short* Bsw = (unsigned short*)ws;              // K*D*2 bytes, swizzled
    float* inv_c = (float*)(ws + (size_t)K * D * 2);        // K floats

    hipMemsetAsync(d_out, 0, sizeof(float), stream);

    prep_centers_kernel<<<(K + 3) / 4, 256, 0, stream>>>(cen, Bsw, inv_c, K, D);

    gemm_loss_kernel<<<N / BM, 512, 0, stream>>>(emb, Bsw, inv_c, labels, out, N, D);
}

// Round 3
// 404.277 us; speedup vs baseline: 2.5602x; 1.0241x over previous
//
#include <hip/hip_runtime.h>
#include <hip/hip_bf16.h>

typedef __bf16 bf16x8 __attribute__((ext_vector_type(8)));
typedef float f32x4 __attribute__((ext_vector_type(4)));
typedef unsigned short u16x4 __attribute__((ext_vector_type(4)));
typedef unsigned short u16x8 __attribute__((ext_vector_type(8)));

#define EPS 1e-8f
#define TAU_INV 10.0f

#define BM 64
#define BN 512
#define BK 32
#define LSTRIDE 516              // 512 + 4 pad for epilogue fp32 tile
#define ABUF 2048                // u16 per A buffer: 64 rows * 32 k

__device__ __forceinline__ u16x4 cvt_bf16x4(f32x4 v) {
    u16x4 u;
    u[0] = __builtin_bit_cast(unsigned short, __float2bfloat16(v[0]));
    u[1] = __builtin_bit_cast(unsigned short, __float2bfloat16(v[1]));
    u[2] = __builtin_bit_cast(unsigned short, __float2bfloat16(v[2]));
    u[3] = __builtin_bit_cast(unsigned short, __float2bfloat16(v[3]));
    return u;
}

// non-temporal f32x4 load: A streams through L2 with evict-first policy so
// the 1MB Bsw table stays L2-resident (B refetch was ~1GB of HBM traffic).
__device__ __forceinline__ f32x4 ldnt_f32x4(const float* p) {
    return __builtin_nontemporal_load((const f32x4*)p);
}

// ---------------------------------------------------------------------------
// prep: centers -> bf16 in MFMA-granule-swizzled order + inv norms.
// Bsw granule (kt,nt,q): 16B at ((kt*32 + nt)*64 + r16 + q*16)*8 u16,
// holding B[row][kt*32 + q*8 .. +8]. One wave per row; lane i owns k=i*16..+16.
// This is EXACT per-wave MFMA B-fragment order: a wave's fragment for
// (kt, nt) is the contiguous 1KB at ((kt*32+nt)*64 + lane)*8.
// ---------------------------------------------------------------------------
__global__ __launch_bounds__(256) void prep_centers_kernel(
    const float* __restrict__ cen, unsigned short* __restrict__ Bsw,
    float* __restrict__ inv_c, int K, int D)
{
    const int wave = threadIdx.x >> 6;
    const int lane = threadIdx.x & 63;
    const int row  = blockIdx.x * 4 + wave;
    if (row >= K) return;

    const float* src = cen + (size_t)row * D + lane * 16;
    const int kt = lane >> 1;
    const int nt = row >> 4;
    const int r16 = row & 15;
    const int q0 = (lane & 1) * 2;

    float ss = 0.0f;
    u16x8 g[2];
    #pragma unroll
    for (int h = 0; h < 2; ++h) {
        #pragma unroll
        for (int j = 0; j < 2; ++j) {
            float4 v = *(const float4*)(src + h * 8 + j * 4);
            ss += v.x * v.x + v.y * v.y + v.z * v.z + v.w * v.w;
            g[h][j * 4 + 0] = __builtin_bit_cast(unsigned short, __float2bfloat16(v.x));
            g[h][j * 4 + 1] = __builtin_bit_cast(unsigned short, __float2bfloat16(v.y));
            g[h][j * 4 + 2] = __builtin_bit_cast(unsigned short, __float2bfloat16(v.z));
            g[h][j * 4 + 3] = __builtin_bit_cast(unsigned short, __float2bfloat16(v.w));
        }
        size_t off = ((size_t)(kt * 32 + nt) * 64 + r16 + (q0 + h) * 16) * 8;
        *(u16x8*)(Bsw + off) = g[h];
    }
    #pragma unroll
    for (int off = 32; off; off >>= 1) ss += __shfl_xor(ss, off);
    if (lane == 0)
        inv_c[row] = (1.0f / fmaxf(sqrtf(ss), EPS)) * TAU_INV; // fold 1/tau
}

// ---------------------------------------------------------------------------
// fused GEMM + log-softmax + NLL.
// 64 rows x all 512 centers; 512 threads = 8 waves, wave w owns cols w*64..+64.
// B fragments load global->VGPR directly (Bsw is fragment-ordered, 1KB
// coalesced per wave-load, L2-resident thanks to NT A-loads).
// Only A (fp32->bf16 convert + ssq) goes through LDS, double-buffered.
// ---------------------------------------------------------------------------
__global__ __launch_bounds__(512, 4) void gemm_loss_kernel(
    const float* __restrict__ Afp, const unsigned short* __restrict__ Bsw,
    const float* __restrict__ inv_c, const int* __restrict__ labels,
    float* __restrict__ out, int N, int D)
{
    __shared__ union {
        unsigned short t[2 * ABUF];    // A staging (8 KB)
        float L[16 * LSTRIDE];         // epilogue overlay (33 KB)
    } sm;
    __shared__ float inv_e_s[BM];
    __shared__ float blockLoss;

    const int tid  = threadIdx.x;
    const int wave = tid >> 6;
    const int lane = tid & 63;
    const int quad = lane >> 4;
    const int tq   = lane & 15;
    const int blockRow = blockIdx.x * BM;

    // ---- A staging map: thread owns (row=tid>>3, float4 slice aj=tid&7) ----
    const int ar   = tid >> 3;        // 0..63
    const int aj   = tid & 7;         // 0..7
    const int a_q  = aj >> 1, a_jl = aj & 1;
    const int a_r16 = ar & 15;
    const int a_woff = (ar >> 4) * 512 + ((a_r16 ^ (2 * a_q)) + a_q * 16) * 8 + a_jl * 4;
    const float* ag = Afp + (size_t)(blockRow + ar) * D + aj * 4;

    // ---- B fragment base: wave's nt tiles are wave*4 + i (i=0..3) ----
    // frag(kt, i) = 16B at bbase + kt*16384 + i*512   (u16 units)
    const unsigned short* bbase = Bsw + (size_t)(wave * 4) * 512 + lane * 8;

    // ---- A fragment read offsets (buffer-relative, kt-invariant) ----
    const int a_rslot = (tq ^ (2 * quad)) + quad * 16;
    int aro[4];
    #pragma unroll
    for (int mt = 0; mt < 4; ++mt) aro[mt] = mt * 512 + a_rslot * 8;

    f32x4 acc[4][4];
    #pragma unroll
    for (int mt = 0; mt < 4; ++mt)
        #pragma unroll
        for (int nt = 0; nt < 4; ++nt)
            acc[mt][nt] = (f32x4){0.f, 0.f, 0.f, 0.f};
    float ssq = 0.0f;
    if (tid == 0) blockLoss = 0.0f;

    const int nK = D / BK;   // 32

    // ---- prologue: stage A kt=0 into buf0 ----
    {
        f32x4 v = ldnt_f32x4(ag);
        ssq += v[0] * v[0] + v[1] * v[1] + v[2] * v[2] + v[3] * v[3];
        *(u16x4*)&sm.t[a_woff] = cvt_bf16x4(v);
    }

    for (int kt = 0; kt < nK; ++kt) {
        __syncthreads();   // A buf[kt] staged & visible; buf[kt+1] free
        unsigned short* cur = &sm.t[(kt & 1) * ABUF];
        unsigned short* nxt = &sm.t[((kt + 1) & 1) * ABUF];

        // B fragments for this kt: 4 coalesced 1KB wave-loads, L2-resident
        bf16x8 bfv[4];
        const unsigned short* bk = bbase + (size_t)kt * 16384;
        #pragma unroll
        for (int i = 0; i < 4; ++i)
            bfv[i] = *(const bf16x8*)(bk + i * 512);

        f32x4 v;
        const bool hn = (kt + 1) < nK;
        if (hn) v = ldnt_f32x4(ag + (kt + 1) * BK);   // A prefetch (NT)

        bf16x8 af[4];
        #pragma unroll
        for (int mt = 0; mt < 4; ++mt) af[mt] = *(const bf16x8*)(cur + aro[mt]);

        #pragma unroll
        for (int nt = 0; nt < 4; ++nt)     // nt-outer: bfv[nt] needed latest
            #pragma unroll
            for (int mt = 0; mt < 4; ++mt)
                acc[mt][nt] = __builtin_amdgcn_mfma_f32_16x16x32_bf16(
                    af[mt], bfv[nt], acc[mt][nt], 0, 0, 0);

        if (hn) {   // A-load latency hidden behind the MFMA block
            ssq += v[0] * v[0] + v[1] * v[1] + v[2] * v[2] + v[3] * v[3];
            *(u16x4*)(nxt + a_woff) = cvt_bf16x4(v);
        }
    }

    // ---- row inverse norms: reduce 8 k-slice partials per row ----
    ssq += __shfl_xor(ssq, 1);
    ssq += __shfl_xor(ssq, 2);
    ssq += __shfl_xor(ssq, 4);
    if (aj == 0) inv_e_s[ar] = 1.0f / fmaxf(sqrtf(ssq), EPS);

    // ---- epilogue: scale + per-16-row logsumexp + NLL ----
    float ic[4];
    #pragma unroll
    for (int nt = 0; nt < 4; ++nt)
        ic[nt] = inv_c[wave * 64 + nt * 16 + tq];
    const float invN = 1.0f / (float)N;

    for (int g = 0; g < 4; ++g) {
        __syncthreads();
        float ie[4];
        #pragma unroll
        for (int r = 0; r < 4; ++r)
            ie[r] = inv_e_s[g * 16 + quad * 4 + r];
        #pragma unroll
        for (int nt = 0; nt < 4; ++nt) {
            int col = wave * 64 + nt * 16 + tq;
            #pragma unroll
            for (int r = 0; r < 4; ++r)
                sm.L[(quad * 4 + r) * LSTRIDE + col] = acc[g][nt][r] * ie[r] * ic[nt];
        }
        __syncthreads();
        #pragma unroll
        for (int rr = 0; rr < 2; ++rr) {
            int rl = wave * 2 + rr;
            int grow = blockRow + g * 16 + rl;
            float vals[8];
            float vmax = -3.0e38f;
            #pragma unroll
            for (int j = 0; j < 8; ++j) {
                vals[j] = sm.L[rl * LSTRIDE + j * 64 + lane];
                vmax = fmaxf(vmax, vals[j]);
            }
            #pragma unroll
            for (int off = 32; off; off >>= 1) vmax = fmaxf(vmax, __shfl_xor(vmax, off));
            float s = 0.0f;
            #pragma unroll
            for (int j = 0; j < 8; ++j) s += __expf(vals[j] - vmax);
            #pragma unroll
            for (int off = 32; off; off >>= 1) s += __shfl_xor(s, off);
            if (lane == 0) {
                int lab = labels[grow];
                float ll = sm.L[rl * LSTRIDE + lab];
                atomicAdd(&blockLoss, vmax + __logf(s) - ll);
            }
        }
    }
    __syncthreads();
    if (tid == 0) atomicAdd(out, blockLoss * invN);
}

// ---------------------------------------------------------------------------
extern "C" void kernel_launch(void* const* d_in, const int* in_sizes, int n_in,
                              void* d_out, int out_size, void* d_ws, size_t ws_size,
                              hipStream_t stream)
{
    const float* emb = (const float*)d_in[0];
    const float* cen = (const float*)d_in[1];
    const int* labels = (const int*)d_in[2];
    float* out = (float*)d_out;

    const int N = in_sizes[2];
    const int D = in_sizes[0] / N;
    const int K = in_sizes[1] / D;

    char* ws = (char*)d_ws;
    unsigned short* Bsw = (unsigned short*)ws;              // K*D*2 bytes, swizzled
    float* inv_c = (float*)(ws + (size_t)K * D * 2);        // K floats

    hipMemsetAsync(d_out, 0, sizeof(float), stream);

    prep_centers_kernel<<<(K + 3) / 4, 256, 0, stream>>>(cen, Bsw, inv_c, K, D);

    gemm_loss_kernel<<<N / BM, 512, 0, stream>>>(emb, Bsw, inv_c, labels, out, N, D);
}